// Round 1
// baseline (97.911 us; speedup 1.0000x reference)
//
#include <hip/hip_runtime.h>

#define HWPIX 4096   // 64*64 pixels
#define SEQ   77
#define NCH   8      // tokens 1..8 (PROMPT_N-2)

// bilinear coord for 64 -> 256 upsample (align_corners=False), i in [0,255]
__device__ __forceinline__ void coord(int i, int& i0, int& i1, float& w) {
    float s = fminf(fmaxf(0.25f * (float)i - 0.375f, 0.0f), 63.0f);
    i0 = (int)s;              // s >= 0 so trunc == floor
    i1 = min(i0 + 1, 63);
    w = s - (float)i0;
}

// Kernel 1: per-channel max of the 256x256 bilinear upsample of attn[:,:,c+1]
__global__ void kmax(const float* __restrict__ attn, float* __restrict__ ws_max) {
    __shared__ float tile[64 * 64];
    __shared__ float red[4];
    const int c = blockIdx.x;      // channel 0..7 -> token c+1
    const int t = threadIdx.x;     // 0..255
    for (int p = t; p < HWPIX; p += 256)
        tile[p] = attn[p * SEQ + (c + 1)];
    __syncthreads();

    // thread t owns upsampled column j = t; iterate rows with rolling row-lerp
    int x0, x1; float wx;
    coord(t, x0, x1, wx);
    float m = -1e30f;
    int cy0 = -99, cy1 = -99;
    float r0 = 0.f, r1 = 0.f;
    for (int i = 0; i < 256; ++i) {
        int y0, y1; float wy;
        coord(i, y0, y1, wy);
        if (y0 != cy0 || y1 != cy1) {
            if (y0 == cy1) r0 = r1;
            else r0 = tile[y0 * 64 + x0] * (1.f - wx) + tile[y0 * 64 + x1] * wx;
            if (y1 == y0) r1 = r0;
            else r1 = tile[y1 * 64 + x0] * (1.f - wx) + tile[y1 * 64 + x1] * wx;
            cy0 = y0; cy1 = y1;
        }
        float u = r0 * (1.f - wy) + r1 * wy;
        m = fmaxf(m, u);
    }
    for (int off = 1; off < 64; off <<= 1)
        m = fmaxf(m, __shfl_xor(m, off, 64));
    if ((t & 63) == 0) red[t >> 6] = m;
    __syncthreads();
    if (t == 0)
        ws_max[c] = fmaxf(fmaxf(red[0], red[1]), fmaxf(red[2], red[3]));
}

// Kernel 2: w[j] = sum_c (+/-1)*gate[c,j].  gate <=> any of the 4 up-pixels
// at rows {4y+1,4y+2} x cols {4x+1,4x+2} >= max_c * thr_c  (downsample weights
// are exactly 0.25 each, so mask>0 <=> any binary pixel set).
__global__ void kgates(const float* __restrict__ attn, const float* __restrict__ ws_max,
                       float* __restrict__ wj) {
    int j = blockIdx.x * blockDim.x + threadIdx.x;
    if (j >= HWPIX) return;
    int y = j >> 6, x = j & 63;
    float acc = 0.f;
    for (int c = 0; c < NCH; ++c) {
        const bool is_tok = (c == 1) || (c == 4);     // tokens 2 and 5
        float lim = ws_max[c] * (is_tok ? 0.85f : 0.95f);
        bool gate = false;
        for (int di = 1; di <= 2; ++di) {
            int y0, y1; float wy;
            coord(4 * y + di, y0, y1, wy);
            for (int dj = 1; dj <= 2; ++dj) {
                int x0, x1; float wx;
                coord(4 * x + dj, x0, x1, wx);
                float v00 = attn[(y0 * 64 + x0) * SEQ + c + 1];
                float v01 = attn[(y0 * 64 + x1) * SEQ + c + 1];
                float v10 = attn[(y1 * 64 + x0) * SEQ + c + 1];
                float v11 = attn[(y1 * 64 + x1) * SEQ + c + 1];
                float top = v00 * (1.f - wx) + v01 * wx;
                float bot = v10 * (1.f - wx) + v11 * wx;
                float u = top * (1.f - wy) + bot * wy;
                gate = gate || (u >= lim);
            }
        }
        if (gate) acc += is_tok ? -1.f : 1.f;
    }
    wj[j] = acc;
}

// Kernel 3: cross-attn retain - erase.  block b handles token s=b+1.
__global__ void kcross(const float* __restrict__ a, const float* __restrict__ ae,
                       float* __restrict__ out) {
    __shared__ float red[4];
    const int s = blockIdx.x + 1;
    const int t = threadIdx.x;
    float sum = 0.f;
    for (int p = t; p < HWPIX; p += 256) {
        float d = a[p * SEQ + s] - ae[p * SEQ + s];
        sum += d * d;
    }
    for (int off = 1; off < 64; off <<= 1) sum += __shfl_xor(sum, off, 64);
    if ((t & 63) == 0) red[t >> 6] = sum;
    __syncthreads();
    if (t == 0) {
        float tot = red[0] + red[1] + red[2] + red[3];
        float sign = (s == 2 || s == 5) ? -1.f : 1.f;
        atomicAdd(out, sign * tot * (1.0f / HWPIX));
    }
}

// Kernel 4: the streaming pass.  sum_f w[f & 4095] * (a[f]-b[f])^2 / 4096.
__global__ void kself(const float4* __restrict__ a, const float4* __restrict__ b,
                      const float* __restrict__ wj, float* __restrict__ out) {
    __shared__ float red[4];
    const int total4 = (HWPIX * HWPIX) / 4;   // 4,194,304 float4s
    int tid = blockIdx.x * blockDim.x + threadIdx.x;
    int stride = gridDim.x * blockDim.x;
    float sum = 0.f;
    for (int f = tid; f < total4; f += stride) {
        float4 va = a[f];
        float4 vb = b[f];
        int jb = (f * 4) & (HWPIX - 1);       // column of first element, %4==0
        float4 vw = *reinterpret_cast<const float4*>(&wj[jb]);
        float d0 = va.x - vb.x, d1 = va.y - vb.y;
        float d2 = va.z - vb.z, d3 = va.w - vb.w;
        sum += vw.x * d0 * d0 + vw.y * d1 * d1 + vw.z * d2 * d2 + vw.w * d3 * d3;
    }
    for (int off = 1; off < 64; off <<= 1) sum += __shfl_xor(sum, off, 64);
    const int t = threadIdx.x;
    if ((t & 63) == 0) red[t >> 6] = sum;
    __syncthreads();
    if (t == 0)
        atomicAdd(out, (red[0] + red[1] + red[2] + red[3]) * (1.0f / HWPIX));
}

extern "C" void kernel_launch(void* const* d_in, const int* in_sizes, int n_in,
                              void* d_out, int out_size, void* d_ws, size_t ws_size,
                              hipStream_t stream) {
    const float* attn   = (const float*)d_in[0];
    const float* attn_e = (const float*)d_in[1];
    const float* sa     = (const float*)d_in[2];
    const float* sae    = (const float*)d_in[3];
    float* out = (float*)d_out;
    float* ws  = (float*)d_ws;
    float* ws_max = ws;        // 8 floats
    float* wj     = ws + 64;   // 4096 floats, 256B-aligned -> float4 loads ok

    hipMemsetAsync(out, 0, sizeof(float), stream);
    kmax  <<<8,    256, 0, stream>>>(attn, ws_max);
    kgates<<<32,   128, 0, stream>>>(attn, ws_max, wj);
    kcross<<<8,    256, 0, stream>>>(attn, attn_e, out);
    kself <<<2048, 256, 0, stream>>>((const float4*)sa, (const float4*)sae, wj, out);
}

// Round 2
// 84.227 us; speedup vs baseline: 1.1625x; 1.1625x over previous
//
#include <hip/hip_runtime.h>

#define HWPIX 4096   // 64*64 pixels
#define SEQ   77

// bilinear coord for 64 -> 256 upsample (align_corners=False), i in [0,255]
__device__ __forceinline__ void coord(int i, int& i0, int& i1, float& w) {
    float s = fminf(fmaxf(0.25f * (float)i - 0.375f, 0.0f), 63.0f);
    i0 = (int)s;              // s >= 0 so trunc == floor
    i1 = min(i0 + 1, 63);
    w = s - (float)i0;
}

// Fused per-channel kernel: block c handles token c+1.
//  - stages attn[:,:,c+1] into LDS (independent unrolled loads)
//  - accumulates the cross-attn MSE term in the same pass
//  - computes max of 256x256 bilinear upsample (rolling row-lerp)
//  - computes gates from the LDS tile, atomicAdd(+/-1) into wj
__global__ __launch_bounds__(256) void kprep(const float* __restrict__ attn,
                                             const float* __restrict__ attn_e,
                                             float* __restrict__ wj,
                                             float* __restrict__ out) {
    __shared__ float tile[HWPIX];
    __shared__ float red_m[4];
    __shared__ float red_s[4];
    __shared__ float smax;
    const int c = blockIdx.x;          // 0..7
    const int tok = c + 1;             // seq column 1..8
    const int t = threadIdx.x;         // 0..255
    const bool is_tok = (tok == 2) || (tok == 5);

    float v[16], ve[16];
    #pragma unroll
    for (int k = 0; k < 16; ++k) {
        int p = t + k * 256;
        v[k]  = attn  [p * SEQ + tok];
        ve[k] = attn_e[p * SEQ + tok];
    }
    float csum = 0.f;
    #pragma unroll
    for (int k = 0; k < 16; ++k) {
        int p = t + k * 256;
        tile[p] = v[k];
        float d = v[k] - ve[k];
        csum += d * d;
    }
    __syncthreads();

    // thread t owns upsampled column t; iterate 256 rows with rolling lerp
    int x0, x1; float wx;
    coord(t, x0, x1, wx);
    float m = -1e30f;
    int cy0 = -99, cy1 = -99;
    float r0 = 0.f, r1 = 0.f;
    for (int i = 0; i < 256; ++i) {
        int y0, y1; float wy;
        coord(i, y0, y1, wy);
        if (y0 != cy0 || y1 != cy1) {
            if (y0 == cy1) r0 = r1;
            else r0 = tile[y0 * 64 + x0] * (1.f - wx) + tile[y0 * 64 + x1] * wx;
            if (y1 == y0) r1 = r0;
            else r1 = tile[y1 * 64 + x0] * (1.f - wx) + tile[y1 * 64 + x1] * wx;
            cy0 = y0; cy1 = y1;
        }
        m = fmaxf(m, r0 * (1.f - wy) + r1 * wy);
    }
    #pragma unroll
    for (int off = 1; off < 64; off <<= 1) {
        m    = fmaxf(m, __shfl_xor(m, off, 64));
        csum +=         __shfl_xor(csum, off, 64);
    }
    if ((t & 63) == 0) { red_m[t >> 6] = m; red_s[t >> 6] = csum; }
    __syncthreads();
    if (t == 0) {
        smax = fmaxf(fmaxf(red_m[0], red_m[1]), fmaxf(red_m[2], red_m[3]));
        float tot = red_s[0] + red_s[1] + red_s[2] + red_s[3];
        atomicAdd(out, (is_tok ? -1.f : 1.f) * tot * (1.0f / HWPIX));
    }
    __syncthreads();

    const float lim = smax * (is_tok ? 0.85f : 0.95f);
    const float sgn = is_tok ? -1.f : 1.f;
    // downsample weights are exactly 0.25 each: mask>0 <=> any of the 4
    // up-pixels at rows {4y+1,4y+2} x cols {4x+1,4x+2} >= max*thr
    #pragma unroll
    for (int k = 0; k < 16; ++k) {
        int j = t + k * 256;
        int y = j >> 6, x = j & 63;
        bool gate = false;
        #pragma unroll
        for (int di = 1; di <= 2; ++di) {
            int y0, y1; float wy;
            coord(4 * y + di, y0, y1, wy);
            #pragma unroll
            for (int dj = 1; dj <= 2; ++dj) {
                int xa, xb; float wxb;
                coord(4 * x + dj, xa, xb, wxb);
                float top = tile[y0 * 64 + xa] * (1.f - wxb) + tile[y0 * 64 + xb] * wxb;
                float bot = tile[y1 * 64 + xa] * (1.f - wxb) + tile[y1 * 64 + xb] * wxb;
                float u = top * (1.f - wy) + bot * wy;
                gate = gate || (u >= lim);
            }
        }
        if (gate) atomicAdd(&wj[j], sgn);
    }
}

// Streaming pass: sum_f w[col(f)] * (a[f]-b[f])^2 / 4096.
// Each thread owns exactly 8 float4 chunks at stride 524288 (= 512 whole
// rows), so the wj column index is CONSTANT per thread -> one vw load.
// All 16 streaming loads issued as an independent batch (MLP).
__global__ __launch_bounds__(256) void kself(const float4* __restrict__ a,
                                             const float4* __restrict__ b,
                                             const float* __restrict__ wj,
                                             float* __restrict__ out) {
    __shared__ float red[4];
    const int t = threadIdx.x;
    const int base = blockIdx.x * 256 + t;     // 0..524287
    const int S = 524288;                      // total4 / 8
    const float4 vw = *reinterpret_cast<const float4*>(&wj[(base & 1023) * 4]);
    float4 va[8], vb[8];
    #pragma unroll
    for (int k = 0; k < 8; ++k) va[k] = a[base + k * S];
    #pragma unroll
    for (int k = 0; k < 8; ++k) vb[k] = b[base + k * S];
    float s0 = 0.f, s1 = 0.f, s2 = 0.f, s3 = 0.f;
    #pragma unroll
    for (int k = 0; k < 8; ++k) {
        float d0 = va[k].x - vb[k].x; s0 += d0 * d0;
        float d1 = va[k].y - vb[k].y; s1 += d1 * d1;
        float d2 = va[k].z - vb[k].z; s2 += d2 * d2;
        float d3 = va[k].w - vb[k].w; s3 += d3 * d3;
    }
    float sum = vw.x * s0 + vw.y * s1 + vw.z * s2 + vw.w * s3;
    #pragma unroll
    for (int off = 1; off < 64; off <<= 1) sum += __shfl_xor(sum, off, 64);
    if ((t & 63) == 0) red[t >> 6] = sum;
    __syncthreads();
    if (t == 0)
        atomicAdd(out, (red[0] + red[1] + red[2] + red[3]) * (1.0f / HWPIX));
}

extern "C" void kernel_launch(void* const* d_in, const int* in_sizes, int n_in,
                              void* d_out, int out_size, void* d_ws, size_t ws_size,
                              hipStream_t stream) {
    const float* attn   = (const float*)d_in[0];
    const float* attn_e = (const float*)d_in[1];
    const float* sa     = (const float*)d_in[2];
    const float* sae    = (const float*)d_in[3];
    float* out = (float*)d_out;
    float* wj  = (float*)d_ws;   // 4096 floats

    hipMemsetAsync(out, 0, sizeof(float), stream);
    hipMemsetAsync(wj, 0, HWPIX * sizeof(float), stream);
    kprep<<<8,    256, 0, stream>>>(attn, attn_e, wj, out);
    kself<<<2048, 256, 0, stream>>>((const float4*)sa, (const float4*)sae, wj, out);
}

// Round 4
// 63.140 us; speedup vs baseline: 1.5507x; 1.3340x over previous
//
#include <hip/hip_runtime.h>

#define HWPIX 4096   // 64*64 pixels
#define SEQ   77

// bilinear coord for 64 -> 256 upsample (align_corners=False), i in [0,255]
__device__ __forceinline__ void coord(int i, int& i0, int& i1, float& w) {
    float s = fminf(fmaxf(0.25f * (float)i - 0.375f, 0.0f), 63.0f);
    i0 = (int)s;              // s >= 0 so trunc == floor
    i1 = min(i0 + 1, 63);
    w = s - (float)i0;
}

// Kernel 1: upsample-max, 64 blocks = 8 channels x 8 row-groups.
// Block (c,g) computes max over upsample rows [32g, 32g+32) of channel c+1;
// needs only input rows 8g-1 .. 8g+8 (10 rows, clamped) -> tiny LDS stage.
// max is exact -> atomicMax on bit pattern gives bit-identical result.
__global__ __launch_bounds__(256) void kmax(const float* __restrict__ attn,
                                            float* __restrict__ ws_max) {
    __shared__ float tile[10 * 64];
    __shared__ float red[4];
    const int c = blockIdx.x >> 3;
    const int g = blockIdx.x & 7;
    const int tok = c + 1;
    const int t = threadIdx.x;
    const int ybase = 8 * g - 1;

    for (int idx = t; idx < 640; idx += 256) {
        int rr = idx >> 6, x = idx & 63;
        int y = min(max(ybase + rr, 0), 63);
        tile[idx] = attn[(y * 64 + x) * SEQ + tok];
    }
    __syncthreads();

    int x0, x1; float wx;
    coord(t, x0, x1, wx);
    float m = -1e30f;
    int cy0 = -99, cy1 = -99;
    float r0 = 0.f, r1 = 0.f;
    for (int i = 32 * g; i < 32 * g + 32; ++i) {
        int y0, y1; float wy;
        coord(i, y0, y1, wy);
        if (y0 != cy0 || y1 != cy1) {
            int l0 = y0 - ybase, l1 = y1 - ybase;   // in [0,9] incl. clamp dups
            if (y0 == cy1) r0 = r1;
            else r0 = tile[l0 * 64 + x0] * (1.f - wx) + tile[l0 * 64 + x1] * wx;
            if (y1 == y0) r1 = r0;
            else r1 = tile[l1 * 64 + x0] * (1.f - wx) + tile[l1 * 64 + x1] * wx;
            cy0 = y0; cy1 = y1;
        }
        m = fmaxf(m, r0 * (1.f - wy) + r1 * wy);
    }
    #pragma unroll
    for (int off = 1; off < 64; off <<= 1)
        m = fmaxf(m, __shfl_xor(m, off, 64));
    if ((t & 63) == 0) red[t >> 6] = m;
    __syncthreads();
    if (t == 0) {
        float bm = fmaxf(fmaxf(red[0], red[1]), fmaxf(red[2], red[3]));
        atomicMax((int*)&ws_max[c], __float_as_int(bm));  // nonneg floats
    }
}

// Kernel 2: gates (blocks 0..127: one pixel/thread for channel bid>>4,
// atomicAdd +/-1 into wj) and cross-attn MSE (blocks 128..135).
// Downsample weights are exactly 0.25 each, so mask>0 <=> any of the 4
// up-pixels at rows {4y+1,4y+2} x cols {4x+1,4x+2} >= max*thr.
__global__ __launch_bounds__(256) void kgates(const float* __restrict__ attn,
                                              const float* __restrict__ attn_e,
                                              const float* __restrict__ ws_max,
                                              float* __restrict__ wj,
                                              float* __restrict__ out) {
    const int bid = blockIdx.x;
    const int t = threadIdx.x;
    if (bid < 128) {
        const int c = bid >> 4;
        const int tok = c + 1;
        const bool is_tok = (tok == 2) || (tok == 5);
        const float lim = ws_max[c] * (is_tok ? 0.85f : 0.95f);
        const int j = (bid & 15) * 256 + t;
        const int y = j >> 6, x = j & 63;
        bool gate = false;
        #pragma unroll
        for (int di = 1; di <= 2; ++di) {
            int y0, y1; float wy;
            coord(4 * y + di, y0, y1, wy);
            #pragma unroll
            for (int dj = 1; dj <= 2; ++dj) {
                int xa, xb; float wxv;
                coord(4 * x + dj, xa, xb, wxv);
                float v00 = attn[(y0 * 64 + xa) * SEQ + tok];
                float v01 = attn[(y0 * 64 + xb) * SEQ + tok];
                float v10 = attn[(y1 * 64 + xa) * SEQ + tok];
                float v11 = attn[(y1 * 64 + xb) * SEQ + tok];
                float top = v00 * (1.f - wxv) + v01 * wxv;
                float bot = v10 * (1.f - wxv) + v11 * wxv;
                float u = top * (1.f - wy) + bot * wy;
                gate = gate || (u >= lim);
            }
        }
        if (gate) atomicAdd(&wj[j], is_tok ? -1.f : 1.f);
    } else {
        __shared__ float red[4];
        const int tok = bid - 128 + 1;
        const bool is_tok = (tok == 2) || (tok == 5);
        float sum = 0.f;
        #pragma unroll
        for (int kk = 0; kk < 16; ++kk) {
            int p = t + kk * 256;
            float d = attn[p * SEQ + tok] - attn_e[p * SEQ + tok];
            sum += d * d;
        }
        #pragma unroll
        for (int off = 1; off < 64; off <<= 1) sum += __shfl_xor(sum, off, 64);
        if ((t & 63) == 0) red[t >> 6] = sum;
        __syncthreads();
        if (t == 0) {
            float tot = red[0] + red[1] + red[2] + red[3];
            atomicAdd(out, (is_tok ? -1.f : 1.f) * tot * (1.0f / HWPIX));
        }
    }
}

// Kernel 3: streaming pass, sum_f w[col(f)] * (a[f]-b[f])^2 / 4096.
// Block b reads ONE contiguous 32KB chunk per array (f = b*2048 + k*256 + t):
// 4096 long streams instead of 32768 x 4KB -> DRAM row locality.
// All strides are multiples of a row (1024 float4s), so col4 = (k&3)*256 + t.
__global__ __launch_bounds__(256) void kself(const float4* __restrict__ a,
                                             const float4* __restrict__ b,
                                             const float* __restrict__ wj,
                                             float* __restrict__ out) {
    __shared__ float red[4];
    const int t = threadIdx.x;
    const int base = blockIdx.x * 2048 + t;
    const float4* wj4 = (const float4*)wj;
    float4 vw[4];
    #pragma unroll
    for (int k = 0; k < 4; ++k) vw[k] = wj4[k * 256 + t];
    float4 va[8], vb[8];
    #pragma unroll
    for (int k = 0; k < 8; ++k) va[k] = a[base + k * 256];
    #pragma unroll
    for (int k = 0; k < 8; ++k) vb[k] = b[base + k * 256];
    float sum = 0.f;
    #pragma unroll
    for (int k = 0; k < 8; ++k) {
        const float4 w4 = vw[k & 3];
        float d0 = va[k].x - vb[k].x;
        float d1 = va[k].y - vb[k].y;
        float d2 = va[k].z - vb[k].z;
        float d3 = va[k].w - vb[k].w;
        sum += w4.x * d0 * d0 + w4.y * d1 * d1 + w4.z * d2 * d2 + w4.w * d3 * d3;
    }
    #pragma unroll
    for (int off = 1; off < 64; off <<= 1) sum += __shfl_xor(sum, off, 64);
    if ((t & 63) == 0) red[t >> 6] = sum;
    __syncthreads();
    if (t == 0)
        atomicAdd(out, (red[0] + red[1] + red[2] + red[3]) * (1.0f / HWPIX));
}

extern "C" void kernel_launch(void* const* d_in, const int* in_sizes, int n_in,
                              void* d_out, int out_size, void* d_ws, size_t ws_size,
                              hipStream_t stream) {
    const float* attn   = (const float*)d_in[0];
    const float* attn_e = (const float*)d_in[1];
    const float* sa     = (const float*)d_in[2];
    const float* sae    = (const float*)d_in[3];
    float* out = (float*)d_out;
    float* wj     = (float*)d_ws;            // 4096 floats
    float* ws_max = (float*)d_ws + HWPIX;    // 8 floats

    hipMemsetAsync(out, 0, sizeof(float), stream);
    hipMemsetAsync(wj, 0, (HWPIX + 8) * sizeof(float), stream);  // wj + ws_max
    kmax  <<<64,   256, 0, stream>>>(attn, ws_max);
    kgates<<<136,  256, 0, stream>>>(attn, attn_e, ws_max, wj, out);
    kself <<<2048, 256, 0, stream>>>((const float4*)sa, (const float4*)sae, wj, out);
}

// Round 6
// 48.489 us; speedup vs baseline: 2.0192x; 1.3021x over previous
//
#include <hip/hip_runtime.h>

#define HWPIX 4096   // 64*64 pixels
#define SEQ   77
#define NBLK_SELF 2048

// bilinear coord for 64 -> 256 upsample (align_corners=False), i in [0,255]
__device__ __forceinline__ void coord(int i, int& i0, int& i1, float& w) {
    float s = fminf(fmaxf(0.25f * (float)i - 0.375f, 0.0f), 63.0f);
    i0 = (int)s;              // s >= 0 so trunc == floor
    i1 = min(i0 + 1, 63);
    w = s - (float)i0;
}

// Kernel 1: upsample-max, 64 blocks = 8 channels x 8 row-groups.
__global__ __launch_bounds__(256) void kmax(const float* __restrict__ attn,
                                            float* __restrict__ ws_max) {
    __shared__ float tile[10 * 64];
    __shared__ float red[4];
    const int c = blockIdx.x >> 3;
    const int g = blockIdx.x & 7;
    const int tok = c + 1;
    const int t = threadIdx.x;
    const int ybase = 8 * g - 1;

    for (int idx = t; idx < 640; idx += 256) {
        int rr = idx >> 6, x = idx & 63;
        int y = min(max(ybase + rr, 0), 63);
        tile[idx] = attn[(y * 64 + x) * SEQ + tok];
    }
    __syncthreads();

    int x0, x1; float wx;
    coord(t, x0, x1, wx);
    float m = -1e30f;
    int cy0 = -99, cy1 = -99;
    float r0 = 0.f, r1 = 0.f;
    for (int i = 32 * g; i < 32 * g + 32; ++i) {
        int y0, y1; float wy;
        coord(i, y0, y1, wy);
        if (y0 != cy0 || y1 != cy1) {
            int l0 = y0 - ybase, l1 = y1 - ybase;
            if (y0 == cy1) r0 = r1;
            else r0 = tile[l0 * 64 + x0] * (1.f - wx) + tile[l0 * 64 + x1] * wx;
            if (y1 == y0) r1 = r0;
            else r1 = tile[l1 * 64 + x0] * (1.f - wx) + tile[l1 * 64 + x1] * wx;
            cy0 = y0; cy1 = y1;
        }
        m = fmaxf(m, r0 * (1.f - wy) + r1 * wy);
    }
    #pragma unroll
    for (int off = 1; off < 64; off <<= 1)
        m = fmaxf(m, __shfl_xor(m, off, 64));
    if ((t & 63) == 0) red[t >> 6] = m;
    __syncthreads();
    if (t == 0) {
        float bm = fmaxf(fmaxf(red[0], red[1]), fmaxf(red[2], red[3]));
        atomicMax((int*)&ws_max[c], __float_as_int(bm));  // nonneg floats
    }
}

// Kernel 2: gates (blocks 0..127) and cross-attn MSE (blocks 128..135,
// accumulated into ws_cross — NOT out, to avoid the final-output atomic).
__global__ __launch_bounds__(256) void kgates(const float* __restrict__ attn,
                                              const float* __restrict__ attn_e,
                                              const float* __restrict__ ws_max,
                                              float* __restrict__ wj,
                                              float* __restrict__ ws_cross) {
    const int bid = blockIdx.x;
    const int t = threadIdx.x;
    if (bid < 128) {
        const int c = bid >> 4;
        const int tok = c + 1;
        const bool is_tok = (tok == 2) || (tok == 5);
        const float lim = ws_max[c] * (is_tok ? 0.85f : 0.95f);
        const int j = (bid & 15) * 256 + t;
        const int y = j >> 6, x = j & 63;
        bool gate = false;
        #pragma unroll
        for (int di = 1; di <= 2; ++di) {
            int y0, y1; float wy;
            coord(4 * y + di, y0, y1, wy);
            #pragma unroll
            for (int dj = 1; dj <= 2; ++dj) {
                int xa, xb; float wxv;
                coord(4 * x + dj, xa, xb, wxv);
                float v00 = attn[(y0 * 64 + xa) * SEQ + tok];
                float v01 = attn[(y0 * 64 + xb) * SEQ + tok];
                float v10 = attn[(y1 * 64 + xa) * SEQ + tok];
                float v11 = attn[(y1 * 64 + xb) * SEQ + tok];
                float top = v00 * (1.f - wxv) + v01 * wxv;
                float bot = v10 * (1.f - wxv) + v11 * wxv;
                float u = top * (1.f - wy) + bot * wy;
                gate = gate || (u >= lim);
            }
        }
        if (gate) atomicAdd(&wj[j], is_tok ? -1.f : 1.f);
    } else {
        __shared__ float red[4];
        const int tok = bid - 128 + 1;
        const bool is_tok = (tok == 2) || (tok == 5);
        float sum = 0.f;
        #pragma unroll
        for (int kk = 0; kk < 16; ++kk) {
            int p = t + kk * 256;
            float d = attn[p * SEQ + tok] - attn_e[p * SEQ + tok];
            sum += d * d;
        }
        #pragma unroll
        for (int off = 1; off < 64; off <<= 1) sum += __shfl_xor(sum, off, 64);
        if ((t & 63) == 0) red[t >> 6] = sum;
        __syncthreads();
        if (t == 0) {
            float tot = red[0] + red[1] + red[2] + red[3];
            atomicAdd(ws_cross, (is_tok ? -1.f : 1.f) * tot);  // raw sum, 8 atomics
        }
    }
}

// Kernel 3: streaming pass. Block b reads ONE contiguous 32KB chunk per array.
// Partial written to ws_partial[b] — plain store, NO contended atomic.
__global__ __launch_bounds__(256) void kself(const float4* __restrict__ a,
                                             const float4* __restrict__ b,
                                             const float* __restrict__ wj,
                                             float* __restrict__ ws_partial) {
    __shared__ float red[4];
    const int t = threadIdx.x;
    const int base = blockIdx.x * 2048 + t;
    const float4* wj4 = (const float4*)wj;
    float4 vw[4];
    #pragma unroll
    for (int k = 0; k < 4; ++k) vw[k] = wj4[k * 256 + t];
    float4 va[8], vb[8];
    #pragma unroll
    for (int k = 0; k < 8; ++k) va[k] = a[base + k * 256];
    #pragma unroll
    for (int k = 0; k < 8; ++k) vb[k] = b[base + k * 256];
    float sum = 0.f;
    #pragma unroll
    for (int k = 0; k < 8; ++k) {
        const float4 w4 = vw[k & 3];
        float d0 = va[k].x - vb[k].x;
        float d1 = va[k].y - vb[k].y;
        float d2 = va[k].z - vb[k].z;
        float d3 = va[k].w - vb[k].w;
        sum += w4.x * d0 * d0 + w4.y * d1 * d1 + w4.z * d2 * d2 + w4.w * d3 * d3;
    }
    #pragma unroll
    for (int off = 1; off < 64; off <<= 1) sum += __shfl_xor(sum, off, 64);
    if ((t & 63) == 0) red[t >> 6] = sum;
    __syncthreads();
    if (t == 0)
        ws_partial[blockIdx.x] = red[0] + red[1] + red[2] + red[3];
}

// Kernel 4: finalize — 1 block sums 2048 partials + cross term, writes out.
__global__ __launch_bounds__(256) void kfin(const float* __restrict__ ws_partial,
                                            const float* __restrict__ ws_cross,
                                            float* __restrict__ out) {
    __shared__ float red[4];
    const int t = threadIdx.x;
    float sum = 0.f;
    #pragma unroll
    for (int k = 0; k < 8; ++k) sum += ws_partial[t + k * 256];
    #pragma unroll
    for (int off = 1; off < 64; off <<= 1) sum += __shfl_xor(sum, off, 64);
    if ((t & 63) == 0) red[t >> 6] = sum;
    __syncthreads();
    if (t == 0) {
        float tot = red[0] + red[1] + red[2] + red[3] + ws_cross[0];
        out[0] = tot * (1.0f / HWPIX);
    }
}

extern "C" void kernel_launch(void* const* d_in, const int* in_sizes, int n_in,
                              void* d_out, int out_size, void* d_ws, size_t ws_size,
                              hipStream_t stream) {
    const float* attn   = (const float*)d_in[0];
    const float* attn_e = (const float*)d_in[1];
    const float* sa     = (const float*)d_in[2];
    const float* sae    = (const float*)d_in[3];
    float* out = (float*)d_out;
    float* wj       = (float*)d_ws;               // [0,    4096) gate weights
    float* ws_max   = wj + HWPIX;                 // [4096, 4104) channel maxima
    float* ws_cross = wj + HWPIX + 8;             // [4104, 4105) cross accumulator
    float* ws_part  = wj + 4352;                  // [4352, 6400) kself partials

    // zero only what is accumulated into (wj, ws_max, ws_cross)
    hipMemsetAsync(wj, 0, (HWPIX + 16) * sizeof(float), stream);
    kmax  <<<64,        256, 0, stream>>>(attn, ws_max);
    kgates<<<136,       256, 0, stream>>>(attn, attn_e, ws_max, wj, ws_cross);
    kself <<<NBLK_SELF, 256, 0, stream>>>((const float4*)sa, (const float4*)sae, wj, ws_part);
    kfin  <<<1,         256, 0, stream>>>(ws_part, ws_cross, out);
}